// Round 14
// baseline (308.032 us; speedup 1.0000x reference)
//
#include <hip/hip_runtime.h>

// Problem constants
#define BATCH 2
#define SEQ   2048
#define EMB   1024
#define NH    16
#define HD    64

typedef __attribute__((ext_vector_type(8))) _Float16 half8;
typedef __attribute__((ext_vector_type(4))) _Float16 half4;
typedef __attribute__((ext_vector_type(4))) float floatx4;

#define LOG2E 1.44269504088896f
#define SCALE2 (0.125f * LOG2E)

#if __has_builtin(__builtin_amdgcn_exp2f)
__device__ __forceinline__ float fexp2(float x) { return __builtin_amdgcn_exp2f(x); }
#else
__device__ __forceinline__ float fexp2(float x) { return exp2f(x); }
#endif

// barrier that drains ONLY LDS ops (no vmcnt): global stores/loads keep
// flying. m201-verified pattern; sched_barrier(0) fences reordering (#18).
__device__ __forceinline__ void lds_barrier() {
    asm volatile("s_waitcnt lgkmcnt(0)" ::: "memory");
    __builtin_amdgcn_s_barrier();
    __builtin_amdgcn_sched_barrier(0);
}

// ---------------------------------------------------------------------------
// Prep 0: fp32 -> fp16 (RNE), vectorized 8 elems/thread (separate pass:
// fusing into GEMM staging regressed +30us in R12 — f32 re-read by 24 blocks)
// ---------------------------------------------------------------------------
__global__ __launch_bounds__(256)
void cvt_f16(const float* __restrict__ in, _Float16* __restrict__ out, int n8) {
    int i = blockIdx.x * 256 + threadIdx.x;
    if (i >= n8) return;
    float4 a = ((const float4*)in)[2 * i];
    float4 b = ((const float4*)in)[2 * i + 1];
    half8 h = {(_Float16)a.x, (_Float16)a.y, (_Float16)a.z, (_Float16)a.w,
               (_Float16)b.x, (_Float16)b.y, (_Float16)b.z, (_Float16)b.w};
    ((half8*)out)[i] = h;
}

// ---------------------------------------------------------------------------
// Prep 1 (single launch): W [K][N] fp32 -> Wt [N][K] fp16 for BOTH weights.
// blockIdx.x < 96 -> Wqkv (N=3072); else -> Wout (N=1024). K=1024 both.
// ---------------------------------------------------------------------------
__global__ __launch_bounds__(256)
void transpose_both(const float* __restrict__ Wqkv, const float* __restrict__ Wout,
                    _Float16* __restrict__ Wh, _Float16* __restrict__ Oh) {
    __shared__ float t[32][33];
    const int K = EMB;
    const float* W; _Float16* o; int N, n0;
    if (blockIdx.x < 96) { W = Wqkv; o = Wh; N = 3 * EMB; n0 = blockIdx.x * 32; }
    else                 { W = Wout; o = Oh; N = EMB;     n0 = (blockIdx.x - 96) * 32; }
    const int k0 = blockIdx.y * 32;
    const int r = threadIdx.x >> 3, c4 = (threadIdx.x & 7) * 4;
    float4 v = *(const float4*)&W[(size_t)(k0 + r) * N + n0 + c4];
    t[r][c4 + 0] = v.x; t[r][c4 + 1] = v.y;
    t[r][c4 + 2] = v.z; t[r][c4 + 3] = v.w;
    __syncthreads();
    half4 hv;
#pragma unroll
    for (int j = 0; j < 4; ++j) hv[j] = (_Float16)t[c4 + j][r];
    *(half4*)&o[(size_t)(n0 + r) * K + k0 + c4] = hv;
}

// ---------------------------------------------------------------------------
// GEMM1 (single fp16 MFMA): qkv = x @ Wqkv + bqkv. [R10-verified form]
// Q columns are PRE-SCALED by 0.125*log2e before the fp16 cast (folds the
// softmax scale into storage; same single-rounding error profile).
// 128x128 tile, BK=32, 4 waves, 64x64/wave. Reg-dbuf LDS (ALD=40),
// ONE __syncthreads per K-step.
// ---------------------------------------------------------------------------
#define ALD 40

__global__ __launch_bounds__(256)
void gemm_qkv_mfma(const _Float16* __restrict__ Xh, const _Float16* __restrict__ Wh,
                   const float* __restrict__ bias,
                   _Float16* __restrict__ Qh, _Float16* __restrict__ Kh,
                   _Float16* __restrict__ Vh) {
    const int K = EMB;   // 1024
    __shared__ _Float16 Ah[2][128 * ALD];
    __shared__ _Float16 Bh[2][128 * ALD];

    const int tid  = threadIdx.x;
    const int wave = tid >> 6, lane = tid & 63;
    const int quad = lane >> 4, lp = lane & 15;

    // XCD-aware swizzle: 24x32 = 768 blocks, 768 % 8 == 0 (bijective).
    const int linear = blockIdx.y * 24 + blockIdx.x;
    const int swz = (linear & 7) * 96 + (linear >> 3);
    const int bx = swz % 24, by = swz / 24;
    const int row0 = by * 128, col0 = bx * 128;
    const int wm = (wave >> 1) * 64, wn = (wave & 1) * 64;

    const int srow = tid >> 2, sseg = (tid & 3) * 8;   // staging map

    floatx4 acc[4][4];
#pragma unroll
    for (int i = 0; i < 4; ++i)
#pragma unroll
        for (int j = 0; j < 4; ++j) acc[i][j] = (floatx4){0.f, 0.f, 0.f, 0.f};

    // prologue: tile 0 -> buf 0
    uint4 a0 = *(const uint4*)&Xh[(size_t)(row0 + srow) * K + sseg];
    uint4 a1 = *(const uint4*)&Xh[(size_t)(row0 + srow + 64) * K + sseg];
    uint4 b0 = *(const uint4*)&Wh[(size_t)(col0 + srow) * K + sseg];
    uint4 b1 = *(const uint4*)&Wh[(size_t)(col0 + srow + 64) * K + sseg];
    *(uint4*)&Ah[0][srow * ALD + sseg] = a0;
    *(uint4*)&Ah[0][(srow + 64) * ALD + sseg] = a1;
    *(uint4*)&Bh[0][srow * ALD + sseg] = b0;
    *(uint4*)&Bh[0][(srow + 64) * ALD + sseg] = b1;

    int cur = 0;
    for (int k0 = 0; k0 < K; k0 += 32) {
        __syncthreads();
        if (k0 + 32 < K) {
            a0 = *(const uint4*)&Xh[(size_t)(row0 + srow) * K + k0 + 32 + sseg];
            a1 = *(const uint4*)&Xh[(size_t)(row0 + srow + 64) * K + k0 + 32 + sseg];
            b0 = *(const uint4*)&Wh[(size_t)(col0 + srow) * K + k0 + 32 + sseg];
            b1 = *(const uint4*)&Wh[(size_t)(col0 + srow + 64) * K + k0 + 32 + sseg];
        }

        half8 ah[4];
#pragma unroll
        for (int mi = 0; mi < 4; ++mi)
            ah[mi] = *(const half8*)&Ah[cur][(wm + mi * 16 + lp) * ALD + quad * 8];
#pragma unroll
        for (int ni = 0; ni < 4; ++ni) {
            half8 bh = *(const half8*)&Bh[cur][(wn + ni * 16 + lp) * ALD + quad * 8];
#pragma unroll
            for (int mi = 0; mi < 4; ++mi)
                acc[mi][ni] = __builtin_amdgcn_mfma_f32_16x16x32_f16(
                    ah[mi], bh, acc[mi][ni], 0, 0, 0);
        }

        if (k0 + 32 < K) {
            *(uint4*)&Ah[cur ^ 1][srow * ALD + sseg] = a0;
            *(uint4*)&Ah[cur ^ 1][(srow + 64) * ALD + sseg] = a1;
            *(uint4*)&Bh[cur ^ 1][srow * ALD + sseg] = b0;
            *(uint4*)&Bh[cur ^ 1][(srow + 64) * ALD + sseg] = b1;
            cur ^= 1;
        }
    }

    // epilogue: scatter fp16 into head-split Q/K/V (Q pre-scaled by SCALE2)
#pragma unroll
    for (int ni = 0; ni < 4; ++ni) {
        const int c = col0 + wn + ni * 16 + lp;    // 0..3071
        const int h = c / 192;
        const int rem = c - h * 192;
        const int which = rem >> 6;                // 0=q 1=k 2=v
        const int d = rem & 63;
        _Float16* __restrict__ P = (which == 0) ? Qh : (which == 1) ? Kh : Vh;
        const float bb = bias[c];
        const float sc = (which == 0) ? SCALE2 : 1.0f;
#pragma unroll
        for (int mi = 0; mi < 4; ++mi) {
            floatx4 a = acc[mi][ni];
#pragma unroll
            for (int r = 0; r < 4; ++r) {
                int m = row0 + wm + mi * 16 + quad * 4 + r;   // b*SEQ + s
                int b = m >> 11, s = m & (SEQ - 1);
                P[((size_t)(b * NH + h) * SEQ + s) * HD + d] =
                    (_Float16)((a[r] + bb) * sc);
            }
        }
    }
}

// ---------------------------------------------------------------------------
// GEMM3 (fp16 MFMA): out = ctx @ Wout + bout, fp32 out. Reg-dbuf, ALD=40.
// ---------------------------------------------------------------------------
__global__ __launch_bounds__(256)
void gemm_out_mfma(const _Float16* __restrict__ Ch, const _Float16* __restrict__ Oh,
                   const float* __restrict__ bias, float* __restrict__ out) {
    const int K = EMB, N = EMB;
    __shared__ _Float16 Ah[2][128 * ALD];
    __shared__ _Float16 Bh[2][128 * ALD];

    const int tid  = threadIdx.x;
    const int wave = tid >> 6, lane = tid & 63;
    const int quad = lane >> 4, lp = lane & 15;

    // XCD swizzle: 8x32 = 256 blocks, 256 % 8 == 0.
    const int linear = blockIdx.y * 8 + blockIdx.x;
    const int swz = (linear & 7) * 32 + (linear >> 3);
    const int bx = swz & 7, by = swz >> 3;
    const int row0 = by * 128, col0 = bx * 128;
    const int wm = (wave >> 1) * 64, wn = (wave & 1) * 64;

    const int srow = tid >> 2, sseg = (tid & 3) * 8;

    floatx4 acc[4][4];
#pragma unroll
    for (int i = 0; i < 4; ++i)
#pragma unroll
        for (int j = 0; j < 4; ++j) acc[i][j] = (floatx4){0.f, 0.f, 0.f, 0.f};

    uint4 a0 = *(const uint4*)&Ch[(size_t)(row0 + srow) * K + sseg];
    uint4 a1 = *(const uint4*)&Ch[(size_t)(row0 + srow + 64) * K + sseg];
    uint4 b0 = *(const uint4*)&Oh[(size_t)(col0 + srow) * K + sseg];
    uint4 b1 = *(const uint4*)&Oh[(size_t)(col0 + srow + 64) * K + sseg];
    *(uint4*)&Ah[0][srow * ALD + sseg] = a0;
    *(uint4*)&Ah[0][(srow + 64) * ALD + sseg] = a1;
    *(uint4*)&Bh[0][srow * ALD + sseg] = b0;
    *(uint4*)&Bh[0][(srow + 64) * ALD + sseg] = b1;

    int cur = 0;
    for (int k0 = 0; k0 < K; k0 += 32) {
        __syncthreads();
        if (k0 + 32 < K) {
            a0 = *(const uint4*)&Ch[(size_t)(row0 + srow) * K + k0 + 32 + sseg];
            a1 = *(const uint4*)&Ch[(size_t)(row0 + srow + 64) * K + k0 + 32 + sseg];
            b0 = *(const uint4*)&Oh[(size_t)(col0 + srow) * K + k0 + 32 + sseg];
            b1 = *(const uint4*)&Oh[(size_t)(col0 + srow + 64) * K + k0 + 32 + sseg];
        }

        half8 ah[4];
#pragma unroll
        for (int mi = 0; mi < 4; ++mi)
            ah[mi] = *(const half8*)&Ah[cur][(wm + mi * 16 + lp) * ALD + quad * 8];
#pragma unroll
        for (int ni = 0; ni < 4; ++ni) {
            half8 bh = *(const half8*)&Bh[cur][(wn + ni * 16 + lp) * ALD + quad * 8];
#pragma unroll
            for (int mi = 0; mi < 4; ++mi)
                acc[mi][ni] = __builtin_amdgcn_mfma_f32_16x16x32_f16(
                    ah[mi], bh, acc[mi][ni], 0, 0, 0);
        }

        if (k0 + 32 < K) {
            *(uint4*)&Ah[cur ^ 1][srow * ALD + sseg] = a0;
            *(uint4*)&Ah[cur ^ 1][(srow + 64) * ALD + sseg] = a1;
            *(uint4*)&Bh[cur ^ 1][srow * ALD + sseg] = b0;
            *(uint4*)&Bh[cur ^ 1][(srow + 64) * ALD + sseg] = b1;
            cur ^= 1;
        }
    }

#pragma unroll
    for (int ni = 0; ni < 4; ++ni) {
        const int c = col0 + wn + ni * 16 + lp;
        const float bb = bias[c];
#pragma unroll
        for (int mi = 0; mi < 4; ++mi) {
            floatx4 a = acc[mi][ni];
#pragma unroll
            for (int r = 0; r < 4; ++r) {
                int m = row0 + wm + mi * 16 + quad * 4 + r;
                out[(size_t)m * N + c] = a[r] + bb;
            }
        }
    }
}

// ---------------------------------------------------------------------------
// MFMA flash attention (fp16), swapped QK^T, log2-domain per-lane softmax.
// PASS 1 this round: K fragments DIRECT from global (L2-resident; 1KB/wave
// coalesced per load), loads hoisted into an array before the MFMA cluster
// (8 in flight), ZERO LDS and ZERO barriers -> waves fully independent.
// (R8's failure was VGPR-40 cap + both passes direct; neither applies here.)
// PASS 2: R13-verified LDS pipeline (K/V reg-dbuf, 1 lgkm-barrier/kt,
// ps stride 72, attn stored direct from f32, setprio on MFMA clusters).
// Q is pre-scaled by 0.125*log2e at GEMM1 (softmax scale folded).
// ---------------------------------------------------------------------------
#define QT 128
#define KT 64
#define LDST 72   // K/V/ps LDS row stride (144 B): 2-way bank alias = free
#define NTILE (SEQ / KT)

__global__ __launch_bounds__(512)
void attn_mfma(const _Float16* __restrict__ Qh,
               const _Float16* __restrict__ Kh,
               const _Float16* __restrict__ Vh,
               float* __restrict__ attn,    // [B,H,S,S]
               _Float16* __restrict__ ctx) { // [B,S,EMB] fp16
    __shared__ _Float16 ksb[2][KT * LDST];    // 18 KB (double-buffered)
    __shared__ _Float16 vtb[2][HD * LDST];    // 18 KB (double-buffered)
    __shared__ _Float16 ps[QT * LDST];        // 18 KB

    const int tid  = threadIdx.x;
    const int wave = tid >> 6, lane = tid & 63;
    const int quad = lane >> 4, lp = lane & 15;
    const int q0 = blockIdx.x * QT;
    const int bh = blockIdx.y;                 // b*NH + h
    const int h  = bh & (NH - 1);
    const float slope2 = exp2f(-0.5f * (float)(h + 1)) * LOG2E;

    const _Float16* Qbase = Qh + ((size_t)bh * SEQ + q0) * HD;
    const _Float16* Kbase = Kh + (size_t)bh * SEQ * HD;
    const _Float16* Vbase = Vh + (size_t)bh * SEQ * HD;

    // Q fragments direct from global (read once, registers thereafter)
    const half8 qa0 = *(const half8*)&Qbase[(size_t)(16 * wave + lp) * HD + quad * 8];
    const half8 qa1 = *(const half8*)&Qbase[(size_t)(16 * wave + lp) * HD + 32 + quad * 8];

    const int qg = q0 + 16 * wave + lp;        // this lane's q row
    const float aq = -slope2 * (float)qg;      // alibi bias (log2 domain)

    // staging map (pass 2): one K/V row-chunk per thread
    const int srow = tid >> 3, sseg = tid & 7;
    const int kvx = srow ^ (sseg << 3);        // V transpose XOR swizzle

    // per-lane online stats (log2 domain), single q per lane
    float m0 = -1e30f, mxv = -1e30f, lsum = 0.f;

    // ========== pass 1: per-lane online max/sum (no LDS, no barriers) =====
    for (int kt = 0; kt < NTILE; ++kt) {
        const _Float16* Kt = Kbase + (size_t)kt * KT * HD;

        // hoist all 8 fragment loads (independent, coalesced 1KB/wave each)
        half8 kf0[4], kf1[4];
#pragma unroll
        for (int t = 0; t < 4; ++t) {
            kf0[t] = *(const half8*)&Kt[(size_t)(16 * t + lp) * HD + quad * 8];
            kf1[t] = *(const half8*)&Kt[(size_t)(16 * t + lp) * HD + 32 + quad * 8];
        }

        floatx4 cc[4];
        __builtin_amdgcn_s_setprio(1);
#pragma unroll
        for (int t = 0; t < 4; ++t) {
            floatx4 c = {0.f, 0.f, 0.f, 0.f};
            c = __builtin_amdgcn_mfma_f32_16x16x32_f16(kf0[t], qa0, c, 0, 0, 0);
            cc[t] = __builtin_amdgcn_mfma_f32_16x16x32_f16(kf1[t], qa1, c, 0, 0, 0);
        }
        __builtin_amdgcn_s_setprio(0);
#pragma unroll
        for (int t = 0; t < 4; ++t) {
            float kb = (float)(kt * KT + 16 * t + 4 * quad);
            float s0 = cc[t][0] + fmaf(slope2, kb,       aq);
            float s1 = cc[t][1] + fmaf(slope2, kb + 1.f, aq);
            float s2 = cc[t][2] + fmaf(slope2, kb + 2.f, aq);
            float s3 = cc[t][3] + fmaf(slope2, kb + 3.f, aq);
            float tm = fmaxf(fmaxf(s0, s1), fmaxf(s2, s3));
            mxv = fmaxf(mxv, tm);
            if (mxv > m0 + 8.f) {              // rare (defer-max, T13)
                lsum *= fexp2(m0 - mxv);
                m0 = mxv;
            }
            lsum += fexp2(s0 - m0) + fexp2(s1 - m0) +
                    fexp2(s2 - m0) + fexp2(s3 - m0);
        }
    }

    // ---- merge (m,l) across the 4 lanes (quads) sharing q; off2=m+log2(l)
    float off2;
    {
        float mm = mxv;
        float ll = lsum * fexp2(m0 - mm);
#pragma unroll
        for (int off = 16; off < 64; off <<= 1) {
            float mo = __shfl_xor(mm, off);
            float lo = __shfl_xor(ll, off);
            float mn = fmaxf(mm, mo);
            ll = ll * fexp2(mm - mn) + lo * fexp2(mo - mn);
            mm = mn;
        }
        off2 = mm + __log2f(ll);
    }

    // ================= pass 2: recompute, write attn, PV =================
    floatx4 o[4];
#pragma unroll
    for (int t = 0; t < 4; ++t) o[t] = (floatx4){0.f, 0.f, 0.f, 0.f};

    float* arow = attn + (size_t)bh * SEQ * SEQ +
                  (size_t)(q0 + 16 * wave + lp) * SEQ + 4 * quad;
    const float aq2 = aq - off2;

    // prologue 2: stage K+V tile 0
    lds_barrier();
    uint4 kreg, vreg;
    kreg = *(const uint4*)&Kbase[(size_t)srow * HD + sseg * 8];
    vreg = *(const uint4*)&Vbase[(size_t)srow * HD + sseg * 8];
    *(uint4*)&ksb[0][srow * LDST + sseg * 8] = kreg;
    {
        union { uint4 u; _Float16 e[8]; } vv; vv.u = vreg;
#pragma unroll
        for (int j = 0; j < 8; ++j)
            vtb[0][(sseg * 8 + j) * LDST + kvx] = vv.e[j];
    }
    lds_barrier();

    int cur = 0;
    for (int kt = 0; kt < NTILE; ++kt) {
        if (kt) lds_barrier();
        if (kt + 1 < NTILE) {
            size_t goff = (size_t)(kt + 1) * KT * HD + (size_t)srow * HD + sseg * 8;
            kreg = *(const uint4*)&Kbase[goff];
            vreg = *(const uint4*)&Vbase[goff];
        }
        const _Float16* ks = ksb[cur];
        const _Float16* vt = vtb[cur];

        // swapped QK^T -> p; attn direct from f32; ps gets fp16 for PV
        __builtin_amdgcn_s_setprio(1);
#pragma unroll
        for (int t = 0; t < 4; ++t) {
            half8 b0 = *(const half8*)&ks[(16 * t + lp) * LDST + quad * 8];
            half8 b1 = *(const half8*)&ks[(16 * t + lp) * LDST + 32 + quad * 8];
            floatx4 c = {0.f, 0.f, 0.f, 0.f};
            c = __builtin_amdgcn_mfma_f32_16x16x32_f16(b0, qa0, c, 0, 0, 0);
            c = __builtin_amdgcn_mfma_f32_16x16x32_f16(b1, qa1, c, 0, 0, 0);
            float kb = (float)(kt * KT + 16 * t + 4 * quad);
            float p0 = fexp2(c[0] + fmaf(slope2, kb,       aq2));
            float p1 = fexp2(c[1] + fmaf(slope2, kb + 1.f, aq2));
            float p2 = fexp2(c[2] + fmaf(slope2, kb + 2.f, aq2));
            float p3 = fexp2(c[3] + fmaf(slope2, kb + 3.f, aq2));
            float4 pw = {p0, p1, p2, p3};
            *(float4*)&arow[kt * KT + 16 * t] = pw;      // coalesced 64B/row
            const int col = 16 * t + 4 * quad;
            half4 ph = {(_Float16)p0, (_Float16)p1, (_Float16)p2, (_Float16)p3};
            *(half4*)&ps[(16 * wave + lp) * LDST + col] = ph;   // ds_write_b64
        }
        __builtin_amdgcn_s_setprio(0);
        // ps is wave-local (rows 16w..16w+15 RW by same wave): no barrier.

        // PV (normal orientation): pa = P A-frag from own-wave ps rows
        half8 pa0 = *(const half8*)&ps[(16 * wave + lp) * LDST + quad * 8];
        half8 pa1 = *(const half8*)&ps[(16 * wave + lp) * LDST + 32 + quad * 8];
        __builtin_amdgcn_s_setprio(1);
#pragma unroll
        for (int t = 0; t < 4; ++t) {
            int g = 2 * t + (lp >> 3);
            half8 vb0 = *(const half8*)&vt[(16 * t + lp) * LDST + ((quad ^ g) << 3)];
            half8 vb1 = *(const half8*)&vt[(16 * t + lp) * LDST + (((quad + 4) ^ g) << 3)];
            o[t] = __builtin_amdgcn_mfma_f32_16x16x32_f16(pa0, vb0, o[t], 0, 0, 0);
            o[t] = __builtin_amdgcn_mfma_f32_16x16x32_f16(pa1, vb1, o[t], 0, 0, 0);
        }
        __builtin_amdgcn_s_setprio(0);

        // write next K/V tile -> other buffer (vmcnt wait via register dep)
        if (kt + 1 < NTILE) {
            *(uint4*)&ksb[cur ^ 1][srow * LDST + sseg * 8] = kreg;
            union { uint4 u; _Float16 e[8]; } vv; vv.u = vreg;
#pragma unroll
            for (int j = 0; j < 8; ++j)
                vtb[cur ^ 1][(sseg * 8 + j) * LDST + kvx] = vv.e[j];
            cur ^= 1;
        }
    }

    // ---- write ctx (fp16): lane holds O[q=16w+4quad+r][d=16t+lp] ----
    const int b = bh >> 4;
#pragma unroll
    for (int t = 0; t < 4; ++t)
#pragma unroll
        for (int r = 0; r < 4; ++r)
            ctx[((size_t)(b * SEQ + q0 + 16 * wave + quad * 4 + r)) * EMB +
                h * HD + 16 * t + lp] = (_Float16)o[t][r];
}

// ---------------------------------------------------------------------------

extern "C" void kernel_launch(void* const* d_in, const int* in_sizes, int n_in,
                              void* d_out, int out_size, void* d_ws, size_t ws_size,
                              hipStream_t stream) {
    const float* x    = (const float*)d_in[0];
    const float* Wqkv = (const float*)d_in[1];
    const float* bqkv = (const float*)d_in[2];
    const float* Wout = (const float*)d_in[3];
    const float* bout = (const float*)d_in[4];

    float* out  = (float*)d_out;
    float* attn = out + (size_t)BATCH * SEQ * EMB;

    // Workspace layout (fp16).
    const size_t HE = (size_t)BATCH * NH * SEQ * HD;   // 4,194,304
    const size_t XE = (size_t)BATCH * SEQ * EMB;       // 4,194,304
    _Float16* Qh = (_Float16*)d_ws;
    _Float16* Kh = Qh + HE;
    _Float16* Vh = Kh + HE;
    _Float16* Ch = Vh + HE;                 // ctx fp16 [B,S,EMB]
    _Float16* Xh = Ch + XE;                 // x fp16 [M,K]
    _Float16* Wh = Xh + XE;                 // Wqkv^T fp16 [3E,K]
    _Float16* Oh = Wh + (size_t)3 * EMB * EMB;  // Wout^T fp16 [E,K]

    // 0) precision prep
    cvt_f16<<<dim3(2048), dim3(256), 0, stream>>>(x, Xh, (int)(XE / 8));
    transpose_both<<<dim3(128, 32), dim3(256), 0, stream>>>(Wqkv, Wout, Wh, Oh);

    // 1) qkv projection (fp16 MFMA) -> fp16 head-split Q/K/V (Q pre-scaled)
    gemm_qkv_mfma<<<dim3(24, 32), dim3(256), 0, stream>>>(
        Xh, Wh, bqkv, Qh, Kh, Vh);

    // 2) MFMA attention (writes attn fp32 + ctx fp16)
    attn_mfma<<<dim3(SEQ / QT, BATCH * NH), dim3(512), 0, stream>>>(
        Qh, Kh, Vh, attn, Ch);

    // 3) out projection (fp16 MFMA, fp32 out)
    gemm_out_mfma<<<dim3(8, 32), dim3(256), 0, stream>>>(Ch, Oh, bout, out);
}

// Round 15
// 256.980 us; speedup vs baseline: 1.1987x; 1.1987x over previous
//
#include <hip/hip_runtime.h>

// Problem constants
#define BATCH 2
#define SEQ   2048
#define EMB   1024
#define NH    16
#define HD    64

typedef __attribute__((ext_vector_type(8))) _Float16 half8;
typedef __attribute__((ext_vector_type(4))) _Float16 half4;
typedef __attribute__((ext_vector_type(4))) float floatx4;

#define LOG2E 1.44269504088896f
#define SCALE2 (0.125f * LOG2E)

#if __has_builtin(__builtin_amdgcn_exp2f)
__device__ __forceinline__ float fexp2(float x) { return __builtin_amdgcn_exp2f(x); }
#else
__device__ __forceinline__ float fexp2(float x) { return exp2f(x); }
#endif

// barrier that drains ONLY LDS ops (no vmcnt): global stores/loads keep
// flying. m201-verified pattern; sched_barrier(0) fences reordering (#18).
__device__ __forceinline__ void lds_barrier() {
    asm volatile("s_waitcnt lgkmcnt(0)" ::: "memory");
    __builtin_amdgcn_s_barrier();
    __builtin_amdgcn_sched_barrier(0);
}

// ---------------------------------------------------------------------------
// Prep 0: fp32 -> fp16 (RNE), vectorized 8 elems/thread (separate pass:
// fusing into GEMM staging regressed +30us in R12 — f32 re-read by 24 blocks)
// ---------------------------------------------------------------------------
__global__ __launch_bounds__(256)
void cvt_f16(const float* __restrict__ in, _Float16* __restrict__ out, int n8) {
    int i = blockIdx.x * 256 + threadIdx.x;
    if (i >= n8) return;
    float4 a = ((const float4*)in)[2 * i];
    float4 b = ((const float4*)in)[2 * i + 1];
    half8 h = {(_Float16)a.x, (_Float16)a.y, (_Float16)a.z, (_Float16)a.w,
               (_Float16)b.x, (_Float16)b.y, (_Float16)b.z, (_Float16)b.w};
    ((half8*)out)[i] = h;
}

// ---------------------------------------------------------------------------
// Prep 1 (single launch): W [K][N] fp32 -> Wt [N][K] fp16 for BOTH weights.
// blockIdx.x < 96 -> Wqkv (N=3072); else -> Wout (N=1024). K=1024 both.
// ---------------------------------------------------------------------------
__global__ __launch_bounds__(256)
void transpose_both(const float* __restrict__ Wqkv, const float* __restrict__ Wout,
                    _Float16* __restrict__ Wh, _Float16* __restrict__ Oh) {
    __shared__ float t[32][33];
    const int K = EMB;
    const float* W; _Float16* o; int N, n0;
    if (blockIdx.x < 96) { W = Wqkv; o = Wh; N = 3 * EMB; n0 = blockIdx.x * 32; }
    else                 { W = Wout; o = Oh; N = EMB;     n0 = (blockIdx.x - 96) * 32; }
    const int k0 = blockIdx.y * 32;
    const int r = threadIdx.x >> 3, c4 = (threadIdx.x & 7) * 4;
    float4 v = *(const float4*)&W[(size_t)(k0 + r) * N + n0 + c4];
    t[r][c4 + 0] = v.x; t[r][c4 + 1] = v.y;
    t[r][c4 + 2] = v.z; t[r][c4 + 3] = v.w;
    __syncthreads();
    half4 hv;
#pragma unroll
    for (int j = 0; j < 4; ++j) hv[j] = (_Float16)t[c4 + j][r];
    *(half4*)&o[(size_t)(n0 + r) * K + k0 + c4] = hv;
}

// ---------------------------------------------------------------------------
// GEMM1 (single fp16 MFMA): qkv = x @ Wqkv + bqkv. [R10/R13-verified form]
// Q columns PRE-SCALED by 0.125*log2e before the fp16 cast (verified R14:
// absmax unchanged; folds the softmax scale into storage).
// 128x128 tile, BK=32, 4 waves, 64x64/wave. Reg-dbuf LDS (ALD=40),
// ONE __syncthreads per K-step.
// ---------------------------------------------------------------------------
#define ALD 40

__global__ __launch_bounds__(256)
void gemm_qkv_mfma(const _Float16* __restrict__ Xh, const _Float16* __restrict__ Wh,
                   const float* __restrict__ bias,
                   _Float16* __restrict__ Qh, _Float16* __restrict__ Kh,
                   _Float16* __restrict__ Vh) {
    const int K = EMB;   // 1024
    __shared__ _Float16 Ah[2][128 * ALD];
    __shared__ _Float16 Bh[2][128 * ALD];

    const int tid  = threadIdx.x;
    const int wave = tid >> 6, lane = tid & 63;
    const int quad = lane >> 4, lp = lane & 15;

    // XCD-aware swizzle: 24x32 = 768 blocks, 768 % 8 == 0 (bijective).
    const int linear = blockIdx.y * 24 + blockIdx.x;
    const int swz = (linear & 7) * 96 + (linear >> 3);
    const int bx = swz % 24, by = swz / 24;
    const int row0 = by * 128, col0 = bx * 128;
    const int wm = (wave >> 1) * 64, wn = (wave & 1) * 64;

    const int srow = tid >> 2, sseg = (tid & 3) * 8;   // staging map

    floatx4 acc[4][4];
#pragma unroll
    for (int i = 0; i < 4; ++i)
#pragma unroll
        for (int j = 0; j < 4; ++j) acc[i][j] = (floatx4){0.f, 0.f, 0.f, 0.f};

    // prologue: tile 0 -> buf 0
    uint4 a0 = *(const uint4*)&Xh[(size_t)(row0 + srow) * K + sseg];
    uint4 a1 = *(const uint4*)&Xh[(size_t)(row0 + srow + 64) * K + sseg];
    uint4 b0 = *(const uint4*)&Wh[(size_t)(col0 + srow) * K + sseg];
    uint4 b1 = *(const uint4*)&Wh[(size_t)(col0 + srow + 64) * K + sseg];
    *(uint4*)&Ah[0][srow * ALD + sseg] = a0;
    *(uint4*)&Ah[0][(srow + 64) * ALD + sseg] = a1;
    *(uint4*)&Bh[0][srow * ALD + sseg] = b0;
    *(uint4*)&Bh[0][(srow + 64) * ALD + sseg] = b1;

    int cur = 0;
    for (int k0 = 0; k0 < K; k0 += 32) {
        __syncthreads();
        if (k0 + 32 < K) {
            a0 = *(const uint4*)&Xh[(size_t)(row0 + srow) * K + k0 + 32 + sseg];
            a1 = *(const uint4*)&Xh[(size_t)(row0 + srow + 64) * K + k0 + 32 + sseg];
            b0 = *(const uint4*)&Wh[(size_t)(col0 + srow) * K + k0 + 32 + sseg];
            b1 = *(const uint4*)&Wh[(size_t)(col0 + srow + 64) * K + k0 + 32 + sseg];
        }

        half8 ah[4];
#pragma unroll
        for (int mi = 0; mi < 4; ++mi)
            ah[mi] = *(const half8*)&Ah[cur][(wm + mi * 16 + lp) * ALD + quad * 8];
#pragma unroll
        for (int ni = 0; ni < 4; ++ni) {
            half8 bh = *(const half8*)&Bh[cur][(wn + ni * 16 + lp) * ALD + quad * 8];
#pragma unroll
            for (int mi = 0; mi < 4; ++mi)
                acc[mi][ni] = __builtin_amdgcn_mfma_f32_16x16x32_f16(
                    ah[mi], bh, acc[mi][ni], 0, 0, 0);
        }

        if (k0 + 32 < K) {
            *(uint4*)&Ah[cur ^ 1][srow * ALD + sseg] = a0;
            *(uint4*)&Ah[cur ^ 1][(srow + 64) * ALD + sseg] = a1;
            *(uint4*)&Bh[cur ^ 1][srow * ALD + sseg] = b0;
            *(uint4*)&Bh[cur ^ 1][(srow + 64) * ALD + sseg] = b1;
            cur ^= 1;
        }
    }

    // epilogue: scatter fp16 into head-split Q/K/V (Q pre-scaled by SCALE2)
#pragma unroll
    for (int ni = 0; ni < 4; ++ni) {
        const int c = col0 + wn + ni * 16 + lp;    // 0..3071
        const int h = c / 192;
        const int rem = c - h * 192;
        const int which = rem >> 6;                // 0=q 1=k 2=v
        const int d = rem & 63;
        _Float16* __restrict__ P = (which == 0) ? Qh : (which == 1) ? Kh : Vh;
        const float bb = bias[c];
        const float sc = (which == 0) ? SCALE2 : 1.0f;
#pragma unroll
        for (int mi = 0; mi < 4; ++mi) {
            floatx4 a = acc[mi][ni];
#pragma unroll
            for (int r = 0; r < 4; ++r) {
                int m = row0 + wm + mi * 16 + quad * 4 + r;   // b*SEQ + s
                int b = m >> 11, s = m & (SEQ - 1);
                P[((size_t)(b * NH + h) * SEQ + s) * HD + d] =
                    (_Float16)((a[r] + bb) * sc);
            }
        }
    }
}

// ---------------------------------------------------------------------------
// GEMM3 (fp16 MFMA): out = ctx @ Wout + bout, fp32 out. Reg-dbuf, ALD=40.
// ---------------------------------------------------------------------------
__global__ __launch_bounds__(256)
void gemm_out_mfma(const _Float16* __restrict__ Ch, const _Float16* __restrict__ Oh,
                   const float* __restrict__ bias, float* __restrict__ out) {
    const int K = EMB, N = EMB;
    __shared__ _Float16 Ah[2][128 * ALD];
    __shared__ _Float16 Bh[2][128 * ALD];

    const int tid  = threadIdx.x;
    const int wave = tid >> 6, lane = tid & 63;
    const int quad = lane >> 4, lp = lane & 15;

    // XCD swizzle: 8x32 = 256 blocks, 256 % 8 == 0.
    const int linear = blockIdx.y * 8 + blockIdx.x;
    const int swz = (linear & 7) * 32 + (linear >> 3);
    const int bx = swz & 7, by = swz >> 3;
    const int row0 = by * 128, col0 = bx * 128;
    const int wm = (wave >> 1) * 64, wn = (wave & 1) * 64;

    const int srow = tid >> 2, sseg = (tid & 3) * 8;

    floatx4 acc[4][4];
#pragma unroll
    for (int i = 0; i < 4; ++i)
#pragma unroll
        for (int j = 0; j < 4; ++j) acc[i][j] = (floatx4){0.f, 0.f, 0.f, 0.f};

    uint4 a0 = *(const uint4*)&Ch[(size_t)(row0 + srow) * K + sseg];
    uint4 a1 = *(const uint4*)&Ch[(size_t)(row0 + srow + 64) * K + sseg];
    uint4 b0 = *(const uint4*)&Oh[(size_t)(col0 + srow) * K + sseg];
    uint4 b1 = *(const uint4*)&Oh[(size_t)(col0 + srow + 64) * K + sseg];
    *(uint4*)&Ah[0][srow * ALD + sseg] = a0;
    *(uint4*)&Ah[0][(srow + 64) * ALD + sseg] = a1;
    *(uint4*)&Bh[0][srow * ALD + sseg] = b0;
    *(uint4*)&Bh[0][(srow + 64) * ALD + sseg] = b1;

    int cur = 0;
    for (int k0 = 0; k0 < K; k0 += 32) {
        __syncthreads();
        if (k0 + 32 < K) {
            a0 = *(const uint4*)&Ch[(size_t)(row0 + srow) * K + k0 + 32 + sseg];
            a1 = *(const uint4*)&Ch[(size_t)(row0 + srow + 64) * K + k0 + 32 + sseg];
            b0 = *(const uint4*)&Oh[(size_t)(col0 + srow) * K + k0 + 32 + sseg];
            b1 = *(const uint4*)&Oh[(size_t)(col0 + srow + 64) * K + k0 + 32 + sseg];
        }

        half8 ah[4];
#pragma unroll
        for (int mi = 0; mi < 4; ++mi)
            ah[mi] = *(const half8*)&Ah[cur][(wm + mi * 16 + lp) * ALD + quad * 8];
#pragma unroll
        for (int ni = 0; ni < 4; ++ni) {
            half8 bh = *(const half8*)&Bh[cur][(wn + ni * 16 + lp) * ALD + quad * 8];
#pragma unroll
            for (int mi = 0; mi < 4; ++mi)
                acc[mi][ni] = __builtin_amdgcn_mfma_f32_16x16x32_f16(
                    ah[mi], bh, acc[mi][ni], 0, 0, 0);
        }

        if (k0 + 32 < K) {
            *(uint4*)&Ah[cur ^ 1][srow * ALD + sseg] = a0;
            *(uint4*)&Ah[cur ^ 1][(srow + 64) * ALD + sseg] = a1;
            *(uint4*)&Bh[cur ^ 1][srow * ALD + sseg] = b0;
            *(uint4*)&Bh[cur ^ 1][(srow + 64) * ALD + sseg] = b1;
            cur ^= 1;
        }
    }

#pragma unroll
    for (int ni = 0; ni < 4; ++ni) {
        const int c = col0 + wn + ni * 16 + lp;
        const float bb = bias[c];
#pragma unroll
        for (int mi = 0; mi < 4; ++mi) {
            floatx4 a = acc[mi][ni];
#pragma unroll
            for (int r = 0; r < 4; ++r) {
                int m = row0 + wm + mi * 16 + quad * 4 + r;
                out[(size_t)m * N + c] = a[r] + bb;
            }
        }
    }
}

// ---------------------------------------------------------------------------
// MFMA flash attention (fp16): R13-verified structure in BOTH passes.
// LDS-staged K/V reg-dbuf, ONE lgkm-only barrier per kt (LDS staging is
// essential: direct-global K fragments = 8x L2 traffic per block — refuted
// R8+R14). Q direct from global (read once); ps stride 72 (>=KT).
// Swapped QK^T, log2-domain per-lane softmax (Q pre-scaled at GEMM1),
// attn stored direct from f32 regs, ps wave-local, setprio on MFMA.
// ---------------------------------------------------------------------------
#define QT 128
#define KT 64
#define LDST 72   // K/V/ps LDS row stride (144 B): 2-way bank alias = free
#define NTILE (SEQ / KT)

__global__ __launch_bounds__(512)
void attn_mfma(const _Float16* __restrict__ Qh,
               const _Float16* __restrict__ Kh,
               const _Float16* __restrict__ Vh,
               float* __restrict__ attn,    // [B,H,S,S]
               _Float16* __restrict__ ctx) { // [B,S,EMB] fp16
    __shared__ _Float16 ksb[2][KT * LDST];    // 18 KB (double-buffered)
    __shared__ _Float16 vtb[2][HD * LDST];    // 18 KB (double-buffered)
    __shared__ _Float16 ps[QT * LDST];        // 18 KB

    const int tid  = threadIdx.x;
    const int wave = tid >> 6, lane = tid & 63;
    const int quad = lane >> 4, lp = lane & 15;
    const int q0 = blockIdx.x * QT;
    const int bh = blockIdx.y;                 // b*NH + h
    const int h  = bh & (NH - 1);
    const float slope2 = exp2f(-0.5f * (float)(h + 1)) * LOG2E;

    const _Float16* Qbase = Qh + ((size_t)bh * SEQ + q0) * HD;
    const _Float16* Kbase = Kh + (size_t)bh * SEQ * HD;
    const _Float16* Vbase = Vh + (size_t)bh * SEQ * HD;

    // Q fragments direct from global (read once, registers thereafter)
    const half8 qa0 = *(const half8*)&Qbase[(size_t)(16 * wave + lp) * HD + quad * 8];
    const half8 qa1 = *(const half8*)&Qbase[(size_t)(16 * wave + lp) * HD + 32 + quad * 8];

    const int qg = q0 + 16 * wave + lp;        // this lane's q row
    const float aq = -slope2 * (float)qg;      // alibi bias (log2 domain)

    // staging map: one K/V row-chunk per thread
    const int srow = tid >> 3, sseg = tid & 7;
    const int kvx = srow ^ (sseg << 3);        // V transpose XOR swizzle

    // per-lane online stats (log2 domain), single q per lane
    float m0 = -1e30f, mxv = -1e30f, lsum = 0.f;

    // prologue: K tile 0 -> buf 0
    uint4 kreg = *(const uint4*)&Kbase[(size_t)srow * HD + sseg * 8];
    *(uint4*)&ksb[0][srow * LDST + sseg * 8] = kreg;
    lds_barrier();

    // ========== pass 1: per-lane online max/sum (1 lgkm-barrier/kt) ======
    int cur = 0;
    for (int kt = 0; kt < NTILE; ++kt) {
        if (kt) lds_barrier();
        if (kt + 1 < NTILE)
            kreg = *(const uint4*)&Kbase[(size_t)(kt + 1) * KT * HD +
                                         (size_t)srow * HD + sseg * 8];
        const _Float16* ks = ksb[cur];

        floatx4 cc[4];
        __builtin_amdgcn_s_setprio(1);
#pragma unroll
        for (int t = 0; t < 4; ++t) {
            half8 b0 = *(const half8*)&ks[(16 * t + lp) * LDST + quad * 8];
            half8 b1 = *(const half8*)&ks[(16 * t + lp) * LDST + 32 + quad * 8];
            floatx4 c = {0.f, 0.f, 0.f, 0.f};
            c = __builtin_amdgcn_mfma_f32_16x16x32_f16(b0, qa0, c, 0, 0, 0);
            cc[t] = __builtin_amdgcn_mfma_f32_16x16x32_f16(b1, qa1, c, 0, 0, 0);
        }
        __builtin_amdgcn_s_setprio(0);
#pragma unroll
        for (int t = 0; t < 4; ++t) {
            float kb = (float)(kt * KT + 16 * t + 4 * quad);
            float s0 = cc[t][0] + fmaf(slope2, kb,       aq);
            float s1 = cc[t][1] + fmaf(slope2, kb + 1.f, aq);
            float s2 = cc[t][2] + fmaf(slope2, kb + 2.f, aq);
            float s3 = cc[t][3] + fmaf(slope2, kb + 3.f, aq);
            float tm = fmaxf(fmaxf(s0, s1), fmaxf(s2, s3));
            mxv = fmaxf(mxv, tm);
            if (mxv > m0 + 8.f) {              // rare (defer-max, T13)
                lsum *= fexp2(m0 - mxv);
                m0 = mxv;
            }
            lsum += fexp2(s0 - m0) + fexp2(s1 - m0) +
                    fexp2(s2 - m0) + fexp2(s3 - m0);
        }

        if (kt + 1 < NTILE) {
            *(uint4*)&ksb[cur ^ 1][srow * LDST + sseg * 8] = kreg;
            cur ^= 1;
        }
    }

    // ---- merge (m,l) across the 4 lanes (quads) sharing q; off2=m+log2(l)
    float off2;
    {
        float mm = mxv;
        float ll = lsum * fexp2(m0 - mm);
#pragma unroll
        for (int off = 16; off < 64; off <<= 1) {
            float mo = __shfl_xor(mm, off);
            float lo = __shfl_xor(ll, off);
            float mn = fmaxf(mm, mo);
            ll = ll * fexp2(mm - mn) + lo * fexp2(mo - mn);
            mm = mn;
        }
        off2 = mm + __log2f(ll);
    }

    // ================= pass 2: recompute, write attn, PV =================
    floatx4 o[4];
#pragma unroll
    for (int t = 0; t < 4; ++t) o[t] = (floatx4){0.f, 0.f, 0.f, 0.f};

    float* arow = attn + (size_t)bh * SEQ * SEQ +
                  (size_t)(q0 + 16 * wave + lp) * SEQ + 4 * quad;
    const float aq2 = aq - off2;

    // prologue 2: stage K+V tile 0 (barrier first: pass-1 ksb reads finish)
    lds_barrier();
    uint4 vreg;
    kreg = *(const uint4*)&Kbase[(size_t)srow * HD + sseg * 8];
    vreg = *(const uint4*)&Vbase[(size_t)srow * HD + sseg * 8];
    *(uint4*)&ksb[0][srow * LDST + sseg * 8] = kreg;
    {
        union { uint4 u; _Float16 e[8]; } vv; vv.u = vreg;
#pragma unroll
        for (int j = 0; j < 8; ++j)
            vtb[0][(sseg * 8 + j) * LDST + kvx] = vv.e[j];
    }
    lds_barrier();

    cur = 0;
    for (int kt = 0; kt < NTILE; ++kt) {
        if (kt) lds_barrier();
        if (kt + 1 < NTILE) {
            size_t goff = (size_t)(kt + 1) * KT * HD + (size_t)srow * HD + sseg * 8;
            kreg = *(const uint4*)&Kbase[goff];
            vreg = *(const uint4*)&Vbase[goff];
        }
        const _Float16* ks = ksb[cur];
        const _Float16* vt = vtb[cur];

        // swapped QK^T -> p; attn direct from f32; ps gets fp16 for PV
        __builtin_amdgcn_s_setprio(1);
#pragma unroll
        for (int t = 0; t < 4; ++t) {
            half8 b0 = *(const half8*)&ks[(16 * t + lp) * LDST + quad * 8];
            half8 b1 = *(const half8*)&ks[(16 * t + lp) * LDST + 32 + quad * 8];
            floatx4 c = {0.f, 0.f, 0.f, 0.f};
            c = __builtin_amdgcn_mfma_f32_16x16x32_f16(b0, qa0, c, 0, 0, 0);
            c = __builtin_amdgcn_mfma_f32_16x16x32_f16(b1, qa1, c, 0, 0, 0);
            float kb = (float)(kt * KT + 16 * t + 4 * quad);
            float p0 = fexp2(c[0] + fmaf(slope2, kb,       aq2));
            float p1 = fexp2(c[1] + fmaf(slope2, kb + 1.f, aq2));
            float p2 = fexp2(c[2] + fmaf(slope2, kb + 2.f, aq2));
            float p3 = fexp2(c[3] + fmaf(slope2, kb + 3.f, aq2));
            float4 pw = {p0, p1, p2, p3};
            *(float4*)&arow[kt * KT + 16 * t] = pw;      // coalesced 64B/row
            const int col = 16 * t + 4 * quad;
            half4 ph = {(_Float16)p0, (_Float16)p1, (_Float16)p2, (_Float16)p3};
            *(half4*)&ps[(16 * wave + lp) * LDST + col] = ph;   // ds_write_b64
        }
        __builtin_amdgcn_s_setprio(0);
        // ps is wave-local (rows 16w..16w+15 RW by same wave): no barrier.

        // PV (normal orientation): pa = P A-frag from own-wave ps rows
        half8 pa0 = *(const half8*)&ps[(16 * wave + lp) * LDST + quad * 8];
        half8 pa1 = *(const half8*)&ps[(16 * wave + lp) * LDST + 32 + quad * 8];
        __builtin_amdgcn_s_setprio(1);
#pragma unroll
        for (int t = 0; t < 4; ++t) {
            int g = 2 * t + (lp >> 3);
            half8 vb0 = *(const half8*)&vt[(16 * t + lp) * LDST + ((quad ^ g) << 3)];
            half8 vb1 = *(const half8*)&vt[(16 * t + lp) * LDST + (((quad + 4) ^ g) << 3)];
            o[t] = __builtin_amdgcn_mfma_f32_16x16x32_f16(pa0, vb0, o[t], 0, 0, 0);
            o[t] = __builtin_amdgcn_mfma_f32_16x16x32_f16(pa1, vb1, o[t], 0, 0, 0);
        }
        __builtin_amdgcn_s_setprio(0);

        // write next K/V tile -> other buffer (vmcnt wait via register dep)
        if (kt + 1 < NTILE) {
            *(uint4*)&ksb[cur ^ 1][srow * LDST + sseg * 8] = kreg;
            union { uint4 u; _Float16 e[8]; } vv; vv.u = vreg;
#pragma unroll
            for (int j = 0; j < 8; ++j)
                vtb[cur ^ 1][(sseg * 8 + j) * LDST + kvx] = vv.e[j];
            cur ^= 1;
        }
    }

    // ---- write ctx (fp16): lane holds O[q=16w+4quad+r][d=16t+lp] ----
    const int b = bh >> 4;
#pragma unroll
    for (int t = 0; t < 4; ++t)
#pragma unroll
        for (int r = 0; r < 4; ++r)
            ctx[((size_t)(b * SEQ + q0 + 16 * wave + quad * 4 + r)) * EMB +
                h * HD + 16 * t + lp] = (_Float16)o[t][r];
}

// ---------------------------------------------------------------------------

extern "C" void kernel_launch(void* const* d_in, const int* in_sizes, int n_in,
                              void* d_out, int out_size, void* d_ws, size_t ws_size,
                              hipStream_t stream) {
    const float* x    = (const float*)d_in[0];
    const float* Wqkv = (const float*)d_in[1];
    const float* bqkv = (const float*)d_in[2];
    const float* Wout = (const float*)d_in[3];
    const float* bout = (const float*)d_in[4];

    float* out  = (float*)d_out;
    float* attn = out + (size_t)BATCH * SEQ * EMB;

    // Workspace layout (fp16).
    const size_t HE = (size_t)BATCH * NH * SEQ * HD;   // 4,194,304
    const size_t XE = (size_t)BATCH * SEQ * EMB;       // 4,194,304
    _Float16* Qh = (_Float16*)d_ws;
    _Float16* Kh = Qh + HE;
    _Float16* Vh = Kh + HE;
    _Float16* Ch = Vh + HE;                 // ctx fp16 [B,S,EMB]
    _Float16* Xh = Ch + XE;                 // x fp16 [M,K]
    _Float16* Wh = Xh + XE;                 // Wqkv^T fp16 [3E,K]
    _Float16* Oh = Wh + (size_t)3 * EMB * EMB;  // Wout^T fp16 [E,K]

    // 0) precision prep
    cvt_f16<<<dim3(2048), dim3(256), 0, stream>>>(x, Xh, (int)(XE / 8));
    transpose_both<<<dim3(128, 32), dim3(256), 0, stream>>>(Wqkv, Wout, Wh, Oh);

    // 1) qkv projection (fp16 MFMA) -> fp16 head-split Q/K/V (Q pre-scaled)
    gemm_qkv_mfma<<<dim3(24, 32), dim3(256), 0, stream>>>(
        Xh, Wh, bqkv, Qh, Kh, Vh);

    // 2) MFMA attention (writes attn fp32 + ctx fp16)
    attn_mfma<<<dim3(SEQ / QT, BATCH * NH), dim3(512), 0, stream>>>(
        Qh, Kh, Vh, attn, Ch);

    // 3) out projection (fp16 MFMA, fp32 out)
    gemm_out_mfma<<<dim3(8, 32), dim3(256), 0, stream>>>(Ch, Oh, bout, out);
}